// Round 5
// baseline (113.765 us; speedup 1.0000x reference)
//
#include <hip/hip_runtime.h>

#define B 8192
#define F 128
#define H 64

typedef __attribute__((ext_vector_type(8))) short bf16x8;
typedef __attribute__((ext_vector_type(4))) float f32x4;

static __device__ __forceinline__ unsigned short f32_to_bf16_rne(float v) {
    unsigned int u = __float_as_uint(v);
    unsigned int r = (u + 0x7FFFu + ((u >> 16) & 1u)) >> 16;
    return (unsigned short)r;
}
static __device__ __forceinline__ float bf16_to_f32(unsigned short h) {
    return __uint_as_float(((unsigned int)h) << 16);
}

// ---------------------------------------------------------------------------
// Split-bf16 MFMA NAM.  Layer2 = 3x mfma_f32_16x16x32_bf16 (hh + hl + lh).
// All 3 terms required: R3->R4 absmax scaling (0.031->0.0625 as eff err
// 2^-17 -> 2^-16) extrapolates dropping a cross term (2^-9) to absmax ~4-8
// vs threshold 0.345.
// R5: W2 hi/lo fragments pre-packed to d_ws by w2_pack (once, not per-wg 32x);
// nam_main_ws has no LDS / no barrier, loads B-frags via 16 coalesced
// dwordx4; m-tiles fully unrolled (16 indep MFMA chains for the scheduler).
// ---------------------------------------------------------------------------

// ws layout: bf16x8 ws[F][2][512]; slot = (nt*2+ks)*64 + lane, 16 B per slot.
__global__ __launch_bounds__(256) void w2_pack(const float* __restrict__ W2,
                                               bf16x8* __restrict__ ws)
{
    const int f = blockIdx.x;
    const int tid = threadIdx.x;
    const float* W2f = W2 + (size_t)f * H * H;
#pragma unroll
    for (int t = tid; t < 512; t += 256) {
        const int n = t & 63;          // output hidden index (MFMA n)
        const int g = t >> 6;          // h-group: h = g*8 + jj (MFMA k)
        const int nt = n >> 4, c = n & 15;
        const int ks = g >> 2, q = g & 3;
        const int slot = (nt * 2 + ks) * 64 + c + 16 * q;
        bf16x8 hv, lv;
#pragma unroll
        for (int jj = 0; jj < 8; ++jj) {
            const float wv = W2f[(g * 8 + jj) * H + n];
            const unsigned short hi = f32_to_bf16_rne(wv);
            const unsigned short lo = f32_to_bf16_rne(wv - bf16_to_f32(hi));
            hv[jj] = (short)hi;
            lv[jj] = (short)lo;
        }
        ws[((size_t)f * 2 + 0) * 512 + slot] = hv;
        ws[((size_t)f * 2 + 1) * 512 + slot] = lv;
    }
}

__global__ __launch_bounds__(256, 2) void nam_main_ws(
    const float* __restrict__ inputs, const float* __restrict__ W1,
    const float* __restrict__ b1, const bf16x8* __restrict__ wsb,
    const float* __restrict__ b2, const float* __restrict__ W3,
    const float* __restrict__ b3, float* __restrict__ out,
    float* __restrict__ fnn_out)
{
    const int tid = threadIdx.x;
    const int f = blockIdx.y;
    const int b0 = blockIdx.x * 256;

    const int lane = tid & 63;
    const int w    = tid >> 6;
    const int q    = lane >> 4;   // quad
    const int col  = lane & 15;

    // resident B fragments (coalesced 16 B/lane loads, L3-hot)
    bf16x8 bhi[4][2], blo[4][2];
#pragma unroll
    for (int nt = 0; nt < 4; ++nt)
#pragma unroll
        for (int ks = 0; ks < 2; ++ks) {
            const int slot = (nt * 2 + ks) * 64 + lane;
            bhi[nt][ks] = wsb[((size_t)f * 2 + 0) * 512 + slot];
            blo[nt][ks] = wsb[((size_t)f * 2 + 1) * 512 + slot];
        }

    const float* W1f = W1 + f * H;
    const float* b1f = b1 + f * H;
    const float* b2f = b2 + f * H;
    const float* W3f = W3 + f * H;

    // per-lane layer-1 weights: k = ks*32 + q*8 + j  (float4 loads)
    float w1v[16], b1v[16];
#pragma unroll
    for (int ks = 0; ks < 2; ++ks)
#pragma unroll
        for (int j4 = 0; j4 < 2; ++j4) {
            const float4 wv = *(const float4*)&W1f[ks * 32 + q * 8 + j4 * 4];
            const float4 bv = *(const float4*)&b1f[ks * 32 + q * 8 + j4 * 4];
            w1v[ks * 8 + j4 * 4 + 0] = wv.x; w1v[ks * 8 + j4 * 4 + 1] = wv.y;
            w1v[ks * 8 + j4 * 4 + 2] = wv.z; w1v[ks * 8 + j4 * 4 + 3] = wv.w;
            b1v[ks * 8 + j4 * 4 + 0] = bv.x; b1v[ks * 8 + j4 * 4 + 1] = bv.y;
            b1v[ks * 8 + j4 * 4 + 2] = bv.z; b1v[ks * 8 + j4 * 4 + 3] = bv.w;
        }
    float b2v[4], w3v[4];
#pragma unroll
    for (int nt = 0; nt < 4; ++nt) {
        b2v[nt] = b2f[nt * 16 + col];
        w3v[nt] = W3f[nt * 16 + col];
    }
    const float b3f = b3[f];

    float x4[4];
#pragma unroll
    for (int mt = 0; mt < 4; ++mt)
        x4[mt] = inputs[(size_t)(b0 + w * 64 + mt * 16 + col) * F + f];

    // ---- 4 m-tiles of 16 rows per wave, fully unrolled for ILP ----
#pragma unroll
    for (int mt = 0; mt < 4; ++mt) {
        const int rbase = b0 + w * 64 + mt * 16;
        const float x = x4[mt];

        f32x4 acc[4];
#pragma unroll
        for (int nt = 0; nt < 4; ++nt) {
            acc[nt][0] = b2v[nt]; acc[nt][1] = b2v[nt];
            acc[nt][2] = b2v[nt]; acc[nt][3] = b2v[nt];
        }

#pragma unroll
        for (int ks = 0; ks < 2; ++ks) {
            // A-frag: trunc-Dekker split (hi exact-bf16 via truncation,
            // lo = r - hi exact), v_perm pair-packing.
            union { unsigned int u[4]; bf16x8 v; } Ah, Al;
#pragma unroll
            for (int t = 0; t < 4; ++t) {
                const float r0 = fmaxf(fmaf(x, w1v[ks * 8 + 2 * t],     b1v[ks * 8 + 2 * t]),     0.0f);
                const float r1 = fmaxf(fmaf(x, w1v[ks * 8 + 2 * t + 1], b1v[ks * 8 + 2 * t + 1]), 0.0f);
                const unsigned int u0 = __float_as_uint(r0);
                const unsigned int u1 = __float_as_uint(r1);
                const float l0 = r0 - __uint_as_float(u0 & 0xFFFF0000u);
                const float l1 = r1 - __uint_as_float(u1 & 0xFFFF0000u);
                Ah.u[t] = __builtin_amdgcn_perm(u1, u0, 0x07060302);
                Al.u[t] = __builtin_amdgcn_perm(__float_as_uint(l1),
                                                __float_as_uint(l0), 0x07060302);
            }
#pragma unroll
            for (int nt = 0; nt < 4; ++nt) {
                acc[nt] = __builtin_amdgcn_mfma_f32_16x16x32_bf16(Ah.v, bhi[nt][ks], acc[nt], 0, 0, 0);
                acc[nt] = __builtin_amdgcn_mfma_f32_16x16x32_bf16(Ah.v, blo[nt][ks], acc[nt], 0, 0, 0);
                acc[nt] = __builtin_amdgcn_mfma_f32_16x16x32_bf16(Al.v, bhi[nt][ks], acc[nt], 0, 0, 0);
            }
        }

        // epilogue: fnn[row] = sum_n relu(C)*W3[n] + b3; out[row] += fnn
        float s[4];
#pragma unroll
        for (int reg = 0; reg < 4; ++reg) {
            float t = 0.0f;
#pragma unroll
            for (int nt = 0; nt < 4; ++nt)
                t = fmaf(fmaxf(acc[nt][reg], 0.0f), w3v[nt], t);
            s[reg] = t;
        }
#pragma unroll
        for (int m_ = 1; m_ <= 8; m_ <<= 1)
#pragma unroll
            for (int reg = 0; reg < 4; ++reg)
                s[reg] += __shfl_xor(s[reg], m_, 64);
        if (col == 0) {
#pragma unroll
            for (int reg = 0; reg < 4; ++reg) {
                const int row = rbase + 4 * q + reg;
                const float val = s[reg] + b3f;
                fnn_out[(size_t)row * F + f] = val;
                atomicAdd(&out[row], val);
            }
        }
    }
}

// ---- fallback (ws too small): R4 kernel, LDS staging ----
__global__ __launch_bounds__(256, 3) void nam_main_lds(
    const float* __restrict__ inputs, const float* __restrict__ W1,
    const float* __restrict__ b1, const float* __restrict__ W2,
    const float* __restrict__ b2, const float* __restrict__ W3,
    const float* __restrict__ b3, float* __restrict__ out,
    float* __restrict__ fnn_out)
{
    const int tid = threadIdx.x;
    const int f = blockIdx.y;
    const int b0 = blockIdx.x * 256;

    const float* W1f = W1 + f * H;
    const float* b1f = b1 + f * H;
    const float* W2f = W2 + (size_t)f * H * H;
    const float* b2f = b2 + f * H;
    const float* W3f = W3 + f * H;

    __shared__ short bhi_s[512 * 8];
    __shared__ short blo_s[512 * 8];

#pragma unroll
    for (int t = tid; t < 512; t += 256) {
        const int n = t & 63, g = t >> 6;
        const int nt = n >> 4, c = n & 15;
        const int ks = g >> 2, q = g & 3;
        const int slot = (nt * 2 + ks) * 64 + c + 16 * q;
        bf16x8 hv, lv;
#pragma unroll
        for (int jj = 0; jj < 8; ++jj) {
            const float wv = W2f[(g * 8 + jj) * H + n];
            const unsigned short hi = f32_to_bf16_rne(wv);
            const unsigned short lo = f32_to_bf16_rne(wv - bf16_to_f32(hi));
            hv[jj] = (short)hi;
            lv[jj] = (short)lo;
        }
        *(bf16x8*)&bhi_s[slot * 8] = hv;
        *(bf16x8*)&blo_s[slot * 8] = lv;
    }

    const int lane = tid & 63, w = tid >> 6;
    const int q = lane >> 4, col = lane & 15;

    float w1v[16], b1v[16];
#pragma unroll
    for (int ks = 0; ks < 2; ++ks)
#pragma unroll
        for (int j = 0; j < 8; ++j) {
            w1v[ks * 8 + j] = W1f[ks * 32 + q * 8 + j];
            b1v[ks * 8 + j] = b1f[ks * 32 + q * 8 + j];
        }
    float b2v[4], w3v[4];
#pragma unroll
    for (int nt = 0; nt < 4; ++nt) {
        b2v[nt] = b2f[nt * 16 + col];
        w3v[nt] = W3f[nt * 16 + col];
    }
    const float b3f = b3[f];

    float x4[4];
#pragma unroll
    for (int mt = 0; mt < 4; ++mt)
        x4[mt] = inputs[(size_t)(b0 + w * 64 + mt * 16 + col) * F + f];

    __syncthreads();

    bf16x8 bhi[4][2], blo[4][2];
#pragma unroll
    for (int nt = 0; nt < 4; ++nt)
#pragma unroll
        for (int ks = 0; ks < 2; ++ks) {
            const int slot = (nt * 2 + ks) * 64 + lane;
            bhi[nt][ks] = *(bf16x8*)&bhi_s[slot * 8];
            blo[nt][ks] = *(bf16x8*)&blo_s[slot * 8];
        }

#pragma unroll 1
    for (int mt = 0; mt < 4; ++mt) {
        const int rbase = b0 + w * 64 + mt * 16;
        const float x = x4[mt];

        f32x4 acc[4];
#pragma unroll
        for (int nt = 0; nt < 4; ++nt) {
            acc[nt][0] = b2v[nt]; acc[nt][1] = b2v[nt];
            acc[nt][2] = b2v[nt]; acc[nt][3] = b2v[nt];
        }
#pragma unroll
        for (int ks = 0; ks < 2; ++ks) {
            union { unsigned int u[4]; bf16x8 v; } Ah, Al;
#pragma unroll
            for (int t = 0; t < 4; ++t) {
                const float r0 = fmaxf(fmaf(x, w1v[ks * 8 + 2 * t],     b1v[ks * 8 + 2 * t]),     0.0f);
                const float r1 = fmaxf(fmaf(x, w1v[ks * 8 + 2 * t + 1], b1v[ks * 8 + 2 * t + 1]), 0.0f);
                const unsigned int u0 = __float_as_uint(r0);
                const unsigned int u1 = __float_as_uint(r1);
                const float l0 = r0 - __uint_as_float(u0 & 0xFFFF0000u);
                const float l1 = r1 - __uint_as_float(u1 & 0xFFFF0000u);
                Ah.u[t] = __builtin_amdgcn_perm(u1, u0, 0x07060302);
                Al.u[t] = __builtin_amdgcn_perm(__float_as_uint(l1),
                                                __float_as_uint(l0), 0x07060302);
            }
#pragma unroll
            for (int nt = 0; nt < 4; ++nt) {
                acc[nt] = __builtin_amdgcn_mfma_f32_16x16x32_bf16(Ah.v, bhi[nt][ks], acc[nt], 0, 0, 0);
                acc[nt] = __builtin_amdgcn_mfma_f32_16x16x32_bf16(Ah.v, blo[nt][ks], acc[nt], 0, 0, 0);
                acc[nt] = __builtin_amdgcn_mfma_f32_16x16x32_bf16(Al.v, bhi[nt][ks], acc[nt], 0, 0, 0);
            }
        }
        float s[4];
#pragma unroll
        for (int reg = 0; reg < 4; ++reg) {
            float t = 0.0f;
#pragma unroll
            for (int nt = 0; nt < 4; ++nt)
                t = fmaf(fmaxf(acc[nt][reg], 0.0f), w3v[nt], t);
            s[reg] = t;
        }
#pragma unroll
        for (int m_ = 1; m_ <= 8; m_ <<= 1)
#pragma unroll
            for (int reg = 0; reg < 4; ++reg)
                s[reg] += __shfl_xor(s[reg], m_, 64);
        if (col == 0) {
#pragma unroll
            for (int reg = 0; reg < 4; ++reg) {
                const int row = rbase + 4 * q + reg;
                const float val = s[reg] + b3f;
                fnn_out[(size_t)row * F + f] = val;
                atomicAdd(&out[row], val);
            }
        }
    }
}

extern "C" void kernel_launch(void* const* d_in, const int* in_sizes, int n_in,
                              void* d_out, int out_size, void* d_ws, size_t ws_size,
                              hipStream_t stream) {
    const float* inputs = (const float*)d_in[0];
    const float* W1     = (const float*)d_in[1];
    const float* b1     = (const float*)d_in[2];
    const float* W2     = (const float*)d_in[3];
    const float* b2     = (const float*)d_in[4];
    const float* W3     = (const float*)d_in[5];
    const float* b3     = (const float*)d_in[6];

    float* out = (float*)d_out;   // (B,)
    float* fnn = out + B;         // (B, F)

    hipMemsetAsync(out, 0, B * sizeof(float), stream);

    const size_t ws_needed = (size_t)F * 2 * 512 * sizeof(bf16x8);  // 2 MB
    if (ws_size >= ws_needed) {
        bf16x8* wsb = (bf16x8*)d_ws;
        w2_pack<<<dim3(F), 256, 0, stream>>>(W2, wsb);
        nam_main_ws<<<dim3(B / 256, F), 256, 0, stream>>>(
            inputs, W1, b1, wsb, b2, W3, b3, out, fnn);
    } else {
        nam_main_lds<<<dim3(B / 256, F), 256, 0, stream>>>(
            inputs, W1, b1, W2, b2, W3, b3, out, fnn);
    }
}

// Round 6
// 111.319 us; speedup vs baseline: 1.0220x; 1.0220x over previous
//
#include <hip/hip_runtime.h>

#define B 8192
#define F 128
#define H 64

typedef __attribute__((ext_vector_type(8))) short bf16x8;
typedef __attribute__((ext_vector_type(4))) float f32x4;

static __device__ __forceinline__ unsigned short f32_to_bf16_rne(float v) {
    unsigned int u = __float_as_uint(v);
    unsigned int r = (u + 0x7FFFu + ((u >> 16) & 1u)) >> 16;
    return (unsigned short)r;
}
static __device__ __forceinline__ float bf16_to_f32(unsigned short h) {
    return __uint_as_float(((unsigned int)h) << 16);
}

// ---------------------------------------------------------------------------
// Split-bf16 MFMA NAM.  Layer2 = 3x mfma_f32_16x16x32_bf16 (hh + hl + lh).
// R6: persistent waves — each wave owns 256 batch rows (16 m-tiles), so the
// per-wave setup (64-reg B-frag set, W1/b1, b2/W3) is amortized 4x vs R5.
// __launch_bounds__(256,3) caps unified V+AGPR at ~170 so 3 waves/SIMD fit
// (R5's unbounded alloc hit ~204 regs -> 2 waves/SIMD -> latency-bound:
// MfmaUtil 17, VALUBusy 36, occupancy 27%).  x gathers software-pipelined
// one super-tile (4 tiles) ahead.  All 3 split terms required: R3->R4 absmax
// scaling extrapolates dropping a cross term to absmax ~4-8 vs thr 0.345.
// ---------------------------------------------------------------------------

// ws layout: bf16x8 ws[F][2][512]; slot = (nt*2+ks)*64 + lane, 16 B per slot.
__global__ __launch_bounds__(256) void w2_pack(const float* __restrict__ W2,
                                               bf16x8* __restrict__ ws)
{
    const int f = blockIdx.x;
    const int tid = threadIdx.x;
    const float* W2f = W2 + (size_t)f * H * H;
#pragma unroll
    for (int t = tid; t < 512; t += 256) {
        const int n = t & 63;          // output hidden index (MFMA n)
        const int g = t >> 6;          // h-group: h = g*8 + jj (MFMA k)
        const int nt = n >> 4, c = n & 15;
        const int ks = g >> 2, q = g & 3;
        const int slot = (nt * 2 + ks) * 64 + c + 16 * q;
        bf16x8 hv, lv;
#pragma unroll
        for (int jj = 0; jj < 8; ++jj) {
            const float wv = W2f[(g * 8 + jj) * H + n];
            const unsigned short hi = f32_to_bf16_rne(wv);
            const unsigned short lo = f32_to_bf16_rne(wv - bf16_to_f32(hi));
            hv[jj] = (short)hi;
            lv[jj] = (short)lo;
        }
        ws[((size_t)f * 2 + 0) * 512 + slot] = hv;
        ws[((size_t)f * 2 + 1) * 512 + slot] = lv;
    }
}

__global__ __launch_bounds__(256, 3) void nam_main_ws(
    const float* __restrict__ inputs, const float* __restrict__ W1,
    const float* __restrict__ b1, const bf16x8* __restrict__ wsb,
    const float* __restrict__ b2, const float* __restrict__ W3,
    const float* __restrict__ b3, float* __restrict__ out,
    float* __restrict__ fnn_out)
{
    const int tid = threadIdx.x;
    const int f = blockIdx.y;
    const int b0 = blockIdx.x * 1024;   // wg covers 1024 rows; wave covers 256

    const int lane = tid & 63;
    const int w    = tid >> 6;
    const int q    = lane >> 4;   // quad
    const int col  = lane & 15;
    const int rw   = b0 + w * 256;

    // resident B fragments (coalesced 16 B/lane loads, L3-hot; reused by 16 tiles)
    bf16x8 bhi[4][2], blo[4][2];
#pragma unroll
    for (int nt = 0; nt < 4; ++nt)
#pragma unroll
        for (int ks = 0; ks < 2; ++ks) {
            const int slot = (nt * 2 + ks) * 64 + lane;
            bhi[nt][ks] = wsb[((size_t)f * 2 + 0) * 512 + slot];
            blo[nt][ks] = wsb[((size_t)f * 2 + 1) * 512 + slot];
        }

    const float* W1f = W1 + f * H;
    const float* b1f = b1 + f * H;
    const float* b2f = b2 + f * H;
    const float* W3f = W3 + f * H;

    // per-lane layer-1 weights: k = ks*32 + q*8 + j  (float4 loads)
    float w1v[16], b1v[16];
#pragma unroll
    for (int ks = 0; ks < 2; ++ks)
#pragma unroll
        for (int j4 = 0; j4 < 2; ++j4) {
            const float4 wv = *(const float4*)&W1f[ks * 32 + q * 8 + j4 * 4];
            const float4 bv = *(const float4*)&b1f[ks * 32 + q * 8 + j4 * 4];
            w1v[ks * 8 + j4 * 4 + 0] = wv.x; w1v[ks * 8 + j4 * 4 + 1] = wv.y;
            w1v[ks * 8 + j4 * 4 + 2] = wv.z; w1v[ks * 8 + j4 * 4 + 3] = wv.w;
            b1v[ks * 8 + j4 * 4 + 0] = bv.x; b1v[ks * 8 + j4 * 4 + 1] = bv.y;
            b1v[ks * 8 + j4 * 4 + 2] = bv.z; b1v[ks * 8 + j4 * 4 + 3] = bv.w;
        }
    float b2v[4], w3v[4];
#pragma unroll
    for (int nt = 0; nt < 4; ++nt) {
        b2v[nt] = b2f[nt * 16 + col];
        w3v[nt] = W3f[nt * 16 + col];
    }
    const float b3f = b3[f];

    // software-pipelined x gathers: one super-tile (4 tiles) ahead
    float xs[4];
#pragma unroll
    for (int i = 0; i < 4; ++i)
        xs[i] = inputs[(size_t)(rw + i * 16 + col) * F + f];

#pragma unroll 1
    for (int sc = 0; sc < 4; ++sc) {
        float xn[4];
        if (sc < 3) {
#pragma unroll
            for (int i = 0; i < 4; ++i)
                xn[i] = inputs[(size_t)(rw + (sc + 1) * 64 + i * 16 + col) * F + f];
        }

#pragma unroll 1
        for (int i = 0; i < 4; ++i) {
            const int rbase = rw + sc * 64 + i * 16;
            const float x = xs[i];

            f32x4 acc[4];
#pragma unroll
            for (int nt = 0; nt < 4; ++nt) {
                acc[nt][0] = b2v[nt]; acc[nt][1] = b2v[nt];
                acc[nt][2] = b2v[nt]; acc[nt][3] = b2v[nt];
            }

#pragma unroll
            for (int ks = 0; ks < 2; ++ks) {
                // A-frag: trunc-Dekker split, v_perm pair-packing.
                union { unsigned int u[4]; bf16x8 v; } Ah, Al;
#pragma unroll
                for (int t = 0; t < 4; ++t) {
                    const float r0 = fmaxf(fmaf(x, w1v[ks * 8 + 2 * t],     b1v[ks * 8 + 2 * t]),     0.0f);
                    const float r1 = fmaxf(fmaf(x, w1v[ks * 8 + 2 * t + 1], b1v[ks * 8 + 2 * t + 1]), 0.0f);
                    const unsigned int u0 = __float_as_uint(r0);
                    const unsigned int u1 = __float_as_uint(r1);
                    const float l0 = r0 - __uint_as_float(u0 & 0xFFFF0000u);
                    const float l1 = r1 - __uint_as_float(u1 & 0xFFFF0000u);
                    Ah.u[t] = __builtin_amdgcn_perm(u1, u0, 0x07060302);
                    Al.u[t] = __builtin_amdgcn_perm(__float_as_uint(l1),
                                                    __float_as_uint(l0), 0x07060302);
                }
#pragma unroll
                for (int nt = 0; nt < 4; ++nt) {
                    acc[nt] = __builtin_amdgcn_mfma_f32_16x16x32_bf16(Ah.v, bhi[nt][ks], acc[nt], 0, 0, 0);
                    acc[nt] = __builtin_amdgcn_mfma_f32_16x16x32_bf16(Ah.v, blo[nt][ks], acc[nt], 0, 0, 0);
                    acc[nt] = __builtin_amdgcn_mfma_f32_16x16x32_bf16(Al.v, bhi[nt][ks], acc[nt], 0, 0, 0);
                }
            }

            // epilogue: fnn[row] = sum_n relu(C)*W3[n] + b3; out[row] += fnn
            float s[4];
#pragma unroll
            for (int reg = 0; reg < 4; ++reg) {
                float t = 0.0f;
#pragma unroll
                for (int nt = 0; nt < 4; ++nt)
                    t = fmaf(fmaxf(acc[nt][reg], 0.0f), w3v[nt], t);
                s[reg] = t;
            }
#pragma unroll
            for (int m_ = 1; m_ <= 8; m_ <<= 1)
#pragma unroll
                for (int reg = 0; reg < 4; ++reg)
                    s[reg] += __shfl_xor(s[reg], m_, 64);
            if (col == 0) {
#pragma unroll
                for (int reg = 0; reg < 4; ++reg) {
                    const int row = rbase + 4 * q + reg;
                    const float val = s[reg] + b3f;
                    fnn_out[(size_t)row * F + f] = val;
                    atomicAdd(&out[row], val);
                }
            }
        }

#pragma unroll
        for (int i = 0; i < 4; ++i) xs[i] = xn[i];
    }
}

// ---- fallback (ws too small): LDS staging, non-persistent ----
__global__ __launch_bounds__(256, 3) void nam_main_lds(
    const float* __restrict__ inputs, const float* __restrict__ W1,
    const float* __restrict__ b1, const float* __restrict__ W2,
    const float* __restrict__ b2, const float* __restrict__ W3,
    const float* __restrict__ b3, float* __restrict__ out,
    float* __restrict__ fnn_out)
{
    const int tid = threadIdx.x;
    const int f = blockIdx.y;
    const int b0 = blockIdx.x * 256;

    const float* W1f = W1 + f * H;
    const float* b1f = b1 + f * H;
    const float* W2f = W2 + (size_t)f * H * H;
    const float* b2f = b2 + f * H;
    const float* W3f = W3 + f * H;

    __shared__ short bhi_s[512 * 8];
    __shared__ short blo_s[512 * 8];

#pragma unroll
    for (int t = tid; t < 512; t += 256) {
        const int n = t & 63, g = t >> 6;
        const int nt = n >> 4, c = n & 15;
        const int ks = g >> 2, q = g & 3;
        const int slot = (nt * 2 + ks) * 64 + c + 16 * q;
        bf16x8 hv, lv;
#pragma unroll
        for (int jj = 0; jj < 8; ++jj) {
            const float wv = W2f[(g * 8 + jj) * H + n];
            const unsigned short hi = f32_to_bf16_rne(wv);
            const unsigned short lo = f32_to_bf16_rne(wv - bf16_to_f32(hi));
            hv[jj] = (short)hi;
            lv[jj] = (short)lo;
        }
        *(bf16x8*)&bhi_s[slot * 8] = hv;
        *(bf16x8*)&blo_s[slot * 8] = lv;
    }

    const int lane = tid & 63, w = tid >> 6;
    const int q = lane >> 4, col = lane & 15;

    float w1v[16], b1v[16];
#pragma unroll
    for (int ks = 0; ks < 2; ++ks)
#pragma unroll
        for (int j = 0; j < 8; ++j) {
            w1v[ks * 8 + j] = W1f[ks * 32 + q * 8 + j];
            b1v[ks * 8 + j] = b1f[ks * 32 + q * 8 + j];
        }
    float b2v[4], w3v[4];
#pragma unroll
    for (int nt = 0; nt < 4; ++nt) {
        b2v[nt] = b2f[nt * 16 + col];
        w3v[nt] = W3f[nt * 16 + col];
    }
    const float b3f = b3[f];

    float x4[4];
#pragma unroll
    for (int mt = 0; mt < 4; ++mt)
        x4[mt] = inputs[(size_t)(b0 + w * 64 + mt * 16 + col) * F + f];

    __syncthreads();

    bf16x8 bhi[4][2], blo[4][2];
#pragma unroll
    for (int nt = 0; nt < 4; ++nt)
#pragma unroll
        for (int ks = 0; ks < 2; ++ks) {
            const int slot = (nt * 2 + ks) * 64 + lane;
            bhi[nt][ks] = *(bf16x8*)&bhi_s[slot * 8];
            blo[nt][ks] = *(bf16x8*)&blo_s[slot * 8];
        }

#pragma unroll 1
    for (int mt = 0; mt < 4; ++mt) {
        const int rbase = b0 + w * 64 + mt * 16;
        const float x = x4[mt];

        f32x4 acc[4];
#pragma unroll
        for (int nt = 0; nt < 4; ++nt) {
            acc[nt][0] = b2v[nt]; acc[nt][1] = b2v[nt];
            acc[nt][2] = b2v[nt]; acc[nt][3] = b2v[nt];
        }
#pragma unroll
        for (int ks = 0; ks < 2; ++ks) {
            union { unsigned int u[4]; bf16x8 v; } Ah, Al;
#pragma unroll
            for (int t = 0; t < 4; ++t) {
                const float r0 = fmaxf(fmaf(x, w1v[ks * 8 + 2 * t],     b1v[ks * 8 + 2 * t]),     0.0f);
                const float r1 = fmaxf(fmaf(x, w1v[ks * 8 + 2 * t + 1], b1v[ks * 8 + 2 * t + 1]), 0.0f);
                const unsigned int u0 = __float_as_uint(r0);
                const unsigned int u1 = __float_as_uint(r1);
                const float l0 = r0 - __uint_as_float(u0 & 0xFFFF0000u);
                const float l1 = r1 - __uint_as_float(u1 & 0xFFFF0000u);
                Ah.u[t] = __builtin_amdgcn_perm(u1, u0, 0x07060302);
                Al.u[t] = __builtin_amdgcn_perm(__float_as_uint(l1),
                                                __float_as_uint(l0), 0x07060302);
            }
#pragma unroll
            for (int nt = 0; nt < 4; ++nt) {
                acc[nt] = __builtin_amdgcn_mfma_f32_16x16x32_bf16(Ah.v, bhi[nt][ks], acc[nt], 0, 0, 0);
                acc[nt] = __builtin_amdgcn_mfma_f32_16x16x32_bf16(Ah.v, blo[nt][ks], acc[nt], 0, 0, 0);
                acc[nt] = __builtin_amdgcn_mfma_f32_16x16x32_bf16(Al.v, bhi[nt][ks], acc[nt], 0, 0, 0);
            }
        }
        float s[4];
#pragma unroll
        for (int reg = 0; reg < 4; ++reg) {
            float t = 0.0f;
#pragma unroll
            for (int nt = 0; nt < 4; ++nt)
                t = fmaf(fmaxf(acc[nt][reg], 0.0f), w3v[nt], t);
            s[reg] = t;
        }
#pragma unroll
        for (int m_ = 1; m_ <= 8; m_ <<= 1)
#pragma unroll
            for (int reg = 0; reg < 4; ++reg)
                s[reg] += __shfl_xor(s[reg], m_, 64);
        if (col == 0) {
#pragma unroll
            for (int reg = 0; reg < 4; ++reg) {
                const int row = rbase + 4 * q + reg;
                const float val = s[reg] + b3f;
                fnn_out[(size_t)row * F + f] = val;
                atomicAdd(&out[row], val);
            }
        }
    }
}

extern "C" void kernel_launch(void* const* d_in, const int* in_sizes, int n_in,
                              void* d_out, int out_size, void* d_ws, size_t ws_size,
                              hipStream_t stream) {
    const float* inputs = (const float*)d_in[0];
    const float* W1     = (const float*)d_in[1];
    const float* b1     = (const float*)d_in[2];
    const float* W2     = (const float*)d_in[3];
    const float* b2     = (const float*)d_in[4];
    const float* W3     = (const float*)d_in[5];
    const float* b3     = (const float*)d_in[6];

    float* out = (float*)d_out;   // (B,)
    float* fnn = out + B;         // (B, F)

    hipMemsetAsync(out, 0, B * sizeof(float), stream);

    const size_t ws_needed = (size_t)F * 2 * 512 * sizeof(bf16x8);  // 2 MB
    if (ws_size >= ws_needed) {
        bf16x8* wsb = (bf16x8*)d_ws;
        w2_pack<<<dim3(F), 256, 0, stream>>>(W2, wsb);
        nam_main_ws<<<dim3(B / 1024, F), 256, 0, stream>>>(
            inputs, W1, b1, wsb, b2, W3, b3, out, fnn);
    } else {
        nam_main_lds<<<dim3(B / 256, F), 256, 0, stream>>>(
            inputs, W1, b1, W2, b2, W3, b3, out, fnn);
    }
}